// Round 4
// baseline (648.069 us; speedup 1.0000x reference)
//
#include <hip/hip_runtime.h>
#include <hip/hip_bf16.h>

#define KL 1024
#define IL 8192
#define DIMV 128
#define NS 8                 // row strips of 128 (2 rows per lane)
#define TROWS 8320           // skewed rows per strip (max used t=8254) + pad for ring overrun
#define SS2 (TROWS*128)      // floats per strip in c_sk (128 = 64 lanes * 2 rows)
#define NW 129               // 129*64 = 8256 DP steps
#define PF 64                // c prefetch distance (steps) == block size
#define INF __builtin_inff()

typedef __attribute__((ext_vector_type(8))) short v8s;   // bf16x8 MFMA A/B frag
typedef __attribute__((ext_vector_type(4))) float v4f;   // MFMA C/D frag

// ---------------- kernel 1: squared row norms + zero flags ----------------
__global__ __launch_bounds__(256) void knorms(
    const float* __restrict__ kern, const float* __restrict__ xx,
    float* __restrict__ x2, float* __restrict__ k2, int* __restrict__ flags) {
  if (blockIdx.x == 0 && threadIdx.x < NS) flags[threadIdx.x] = 0;
  const int lane = threadIdx.x & 63;
  const int row = blockIdx.x * 4 + (threadIdx.x >> 6);
  const float* src;
  float* dst;
  if (row < IL) { src = xx + (size_t)row * DIMV; dst = x2 + row; }
  else          { src = kern + (size_t)(row - IL) * DIMV; dst = k2 + (row - IL); }
  float2 v = *(const float2*)(src + lane * 2);
  float ss = v.x * v.x + v.y * v.y;
  #pragma unroll
  for (int off = 32; off > 0; off >>= 1) ss += __shfl_down(ss, off, 64);
  if (lane == 0) *dst = ss;
}

// ---------------- kernel 2: MFMA bf16 GEMM -> c, diagonal-skew + row-pair interleave ----
// c_sk[s][t][lane][r] = c(row 128s+2*lane+r, col j) with t = j + lane
__device__ __forceinline__ v8s pack_bf16x8(float4 a, float4 b) {
  union { unsigned int u[4]; v8s v; } r;
  union { __hip_bfloat162 h; unsigned int u; } t;
  t.h = __float22bfloat162_rn(make_float2(a.x, a.y)); r.u[0] = t.u;
  t.h = __float22bfloat162_rn(make_float2(a.z, a.w)); r.u[1] = t.u;
  t.h = __float22bfloat162_rn(make_float2(b.x, b.y)); r.u[2] = t.u;
  t.h = __float22bfloat162_rn(make_float2(b.z, b.w)); r.u[3] = t.u;
  return r.v;
}

__global__ __launch_bounds__(256) void kgemm(
    const float* __restrict__ kern, const float* __restrict__ xx,
    const float* __restrict__ x2, const float* __restrict__ k2,
    float* __restrict__ c_sk) {
  __shared__ float ctile[64 * 64];   // [m=kernel-row][n=x-col], plain (2-way LDS = free)
  const int T = threadIdx.x;
  const int w = T >> 6;
  const int lane = T & 63;
  const int lo = lane & 15;
  const int hi = lane >> 4;
  const int i0 = blockIdx.x * 64;    // DTW columns (x rows)
  const int y  = blockIdx.y;         // 64-row tile index (0..15)
  const int kr0 = y * 64;

  v4f acc[4] = {};
  #pragma unroll
  for (int ks = 0; ks < 4; ks++) {
    const int k = ks * 32 + hi * 8;
    const float* bp = xx + (size_t)(i0 + w * 16 + lo) * DIMV + k;
    v8s bf = pack_bf16x8(*(const float4*)bp, *(const float4*)(bp + 4));
    #pragma unroll
    for (int rt = 0; rt < 4; rt++) {
      const float* ap = kern + (size_t)(kr0 + rt * 16 + lo) * DIMV + k;
      v8s af = pack_bf16x8(*(const float4*)ap, *(const float4*)(ap + 4));
      acc[rt] = __builtin_amdgcn_mfma_f32_16x16x32_bf16(af, bf, acc[rt], 0, 0, 0);
    }
  }
  const float x2v = x2[i0 + w * 16 + lo];
  const int n_local = w * 16 + lo;
  #pragma unroll
  for (int rt = 0; rt < 4; rt++) {
    float4 k2f = *(const float4*)&k2[kr0 + rt * 16 + hi * 4];
    #pragma unroll
    for (int q = 0; q < 4; q++) {
      const int m_local = rt * 16 + hi * 4 + q;
      float cval = fmaxf((&k2f.x)[q] + x2v - 2.f * acc[rt][q], 0.f);
      ctile[m_local * 64 + n_local] = cval;
    }
  }
  __syncthreads();
  // scatter: strip s = y>>1, half = y&1 (lanes 32*half..32*half+31 of the strip)
  // element (di, dk): dk == lane; di = tt - (lane>>1); t = i0 + tt + 32*half
  const int s = y >> 1, half = y & 1;
  const int l_off = lane >> 1;
  float* ob = c_sk + (size_t)s * SS2 + 64 * half + lane;
  #pragma unroll
  for (int q = 0; q < 24; q++) {
    int tt = w + q * 4;              // 0..95 (use <= 94)
    int di = tt - l_off;
    if (tt <= 94 && di >= 0 && di < 64) {
      int t = i0 + tt + 32 * half;
      ob[(size_t)t * 128] = ctile[lane * 64 + di];
    }
  }
}

// ---------------- kernel 3: wavefront DP, 2 rows/lane, all-DPP ----------------
__device__ __forceinline__ float dpp_wave_shr1(float oldv, float src) {
  return __int_as_float(__builtin_amdgcn_update_dpp(
      __float_as_int(oldv), __float_as_int(src), 0x138, 0xF, 0xF, false));
}
__device__ __forceinline__ float dpp_wave_rol1(float src) {
  return __int_as_float(__builtin_amdgcn_update_dpp(
      __float_as_int(src), __float_as_int(src), 0x134, 0xF, 0xF, false));
}
__device__ __forceinline__ float dpp_wave_shl1(float oldv, float src) {
  return __int_as_float(__builtin_amdgcn_update_dpp(
      __float_as_int(oldv), __float_as_int(src), 0x130, 0xF, 0xF, false));
}

__global__ __launch_bounds__(64) void kdp(
    const float* __restrict__ c_sk, float* __restrict__ bound,
    int* __restrict__ flags, float* __restrict__ out) {
  const int s = blockIdx.x;
  const int lane = threadIdx.x;
  const float2* cs = (const float2*)(c_sk + (size_t)s * SS2) + lane;  // step t -> cs[t*64]
  float* bout = bound + (size_t)s * IL;
  const float* bin = bound + (size_t)(s - 1) * IL;

  float2 ring[PF];
  #pragma unroll
  for (int q = 0; q < PF; q++) ring[q] = cs[q * 64];

  float Bv, bb1;
  int fchk = 0x7fffffff;
  if (s > 0) {
    int f;
    do { f = __hip_atomic_load(&flags[s - 1], __ATOMIC_RELAXED, __HIP_MEMORY_SCOPE_AGENT); } while (f < 128);
    Bv  = __hip_atomic_load(&bin[lane],      __ATOMIC_RELAXED, __HIP_MEMORY_SCOPE_AGENT);
    bb1 = __hip_atomic_load(&bin[64 + lane], __ATOMIC_RELAXED, __HIP_MEMORY_SCOPE_AGENT);
    fchk = f;
  } else {
    Bv = INF; bb1 = INF;
  }

  // lane l owns rows 2l (D0) and 2l+1 (D1); Dul = lane l-1's D1 stream (diag for row 2l)
  float D0 = INF, D1 = INF;
  float Dul = (s == 0 && lane == 0) ? 0.f : INF;  // virtual D[-1][-1] seed via diag path
  float Bout = INF;

  for (int W = 0; W < NW; W++) {
    const int t0 = W * 64;
    float bb2 = INF;
    int fnew = fchk;
    if (s > 0 && W < NW - 1) {
      int need = t0 + 128; if (need > IL) need = IL;
      if (fchk < need) {  // slow path: pipeline fill only
        int f;
        do { f = __hip_atomic_load(&flags[s - 1], __ATOMIC_RELAXED, __HIP_MEMORY_SCOPE_AGENT); } while (f < need);
        int rb = t0 + 64; if (rb > IL - 64) rb = IL - 64;
        bb1 = __hip_atomic_load(&bin[rb + lane], __ATOMIC_RELAXED, __HIP_MEMORY_SCOPE_AGENT);
        fchk = f;
      }
      int nb = t0 + 128; if (nb > IL - 64) nb = IL - 64;
      bb2  = __hip_atomic_load(&bin[nb + lane], __ATOMIC_RELAXED, __HIP_MEMORY_SCOPE_AGENT);
      fnew = __hip_atomic_load(&flags[s - 1],   __ATOMIC_RELAXED, __HIP_MEMORY_SCOPE_AGENT);
    }
    if (W >= 1 && W <= 127) {
      #pragma unroll
      for (int tt = 0; tt < 64; tt++) {
        const int t = t0 + tt;
        float2 cv = ring[tt];
        ring[tt] = cs[(size_t)(t + PF) * 64];
        float Dup = dpp_wave_shr1(Bv, D1);      // lane l-1's D1 (prev step); lane0 from feed
        Bv = dpp_wave_rol1(Bv);
        float n0 = cv.x + fminf(fminf(Dul, Dup), D0);
        float n1 = cv.y + fminf(fminf(D0, n0), D1);   // diag=old D0, up=n0, left=D1
        Dul = Dup; D0 = n0; D1 = n1;
        Bout = dpp_wave_shl1(D1, Bout);         // lane63 injects bottom-row value
      }
    } else {
      // masked prologue (W=0) / epilogue (W=128)
      #pragma unroll
      for (int tt = 0; tt < 64; tt++) {
        const int t = t0 + tt;
        float2 cv = ring[tt];
        ring[tt] = cs[(size_t)(t + PF) * 64];
        float Dup = dpp_wave_shr1(Bv, D1);
        Bv = dpp_wave_rol1(Bv);
        float n0 = cv.x + fminf(fminf(Dul, Dup), D0);
        float n1 = cv.y + fminf(fminf(D0, n0), D1);
        Dul = Dup;                               // safe unconditionally (INF streams pre-active)
        const bool act = (t >= lane) && (t - lane < IL);
        if (act) { D0 = n0; D1 = n1; }
        Bout = dpp_wave_shl1(D1, Bout);
      }
    }
    if (s < NS - 1) {
      const int j = t0 + lane - 63;
      if (j >= 0 && j < IL)
        __hip_atomic_store(&bout[j], Bout, __ATOMIC_RELAXED, __HIP_MEMORY_SCOPE_AGENT);
      if (W >= 1 && lane == 0)
        __hip_atomic_store(&flags[s], 64 * (W - 1) + 1, __ATOMIC_RELAXED, __HIP_MEMORY_SCOPE_AGENT);
    }
    if (s > 0) { Bv = bb1; bb1 = bb2; fchk = fnew; }
  }
  if (s < NS - 1) {
    __threadfence();
    if (lane == 0)
      __hip_atomic_store(&flags[s], IL, __ATOMIC_RELAXED, __HIP_MEMORY_SCOPE_AGENT);
  }
  if (s == NS - 1 && lane == 63) out[0] = D1;  // D[K-1][I-1] == optimal path sum
}

extern "C" void kernel_launch(void* const* d_in, const int* in_sizes, int n_in,
                              void* d_out, int out_size, void* d_ws, size_t ws_size,
                              hipStream_t stream) {
  const float* kern = (const float*)d_in[0]; // (1024,128)
  const float* xx   = (const float*)d_in[1]; // (8192,128)
  char* ws = (char*)d_ws;
  const size_t OFF_X2 = (size_t)NS * SS2 * 4;          // c_sk: ~34.1 MB
  const size_t OFF_K2 = OFF_X2 + (size_t)IL * 4;
  const size_t OFF_BD = OFF_K2 + (size_t)KL * 4;
  const size_t OFF_FL = OFF_BD + (size_t)NS * IL * 4;
  float* c_sk  = (float*)ws;
  float* x2    = (float*)(ws + OFF_X2);
  float* k2    = (float*)(ws + OFF_K2);
  float* bnd   = (float*)(ws + OFF_BD);
  int*   flags = (int*)(ws + OFF_FL);

  knorms<<<(IL + KL) / 4, 256, 0, stream>>>(kern, xx, x2, k2, flags);
  kgemm<<<dim3(IL / 64, 16), 256, 0, stream>>>(kern, xx, x2, k2, c_sk);
  kdp<<<NS, 64, 0, stream>>>(c_sk, bnd, flags, (float*)d_out);
}

// Round 5
// 507.052 us; speedup vs baseline: 1.2781x; 1.2781x over previous
//
#include <hip/hip_runtime.h>
#include <hip/hip_bf16.h>

#define KL 1024
#define IL 8192
#define DIMV 128
#define NS 16               // row strips of 64 (1 row per lane)
#define TROWS 8320          // skewed rows allocated per strip (used: t <= 8255)
#define SSTRIDE (TROWS*64)  // floats per strip in c_sk
#define NW 129              // 129 chunks x 64 = 8256 DP steps
#define INF __builtin_inff()

typedef __attribute__((ext_vector_type(8))) short v8s;   // bf16x8 MFMA A/B frag
typedef __attribute__((ext_vector_type(4))) float v4f;   // MFMA C/D frag

// ---------------- kernel 1: squared row norms + zero flags ----------------
__global__ __launch_bounds__(256) void knorms(
    const float* __restrict__ kern, const float* __restrict__ xx,
    float* __restrict__ x2, float* __restrict__ k2, int* __restrict__ flags) {
  if (blockIdx.x == 0 && threadIdx.x < NS) flags[threadIdx.x] = 0;
  const int lane = threadIdx.x & 63;
  const int row = blockIdx.x * 4 + (threadIdx.x >> 6);
  const float* src;
  float* dst;
  if (row < IL) { src = xx + (size_t)row * DIMV; dst = x2 + row; }
  else          { src = kern + (size_t)(row - IL) * DIMV; dst = k2 + (row - IL); }
  float2 v = *(const float2*)(src + lane * 2);
  float ss = v.x * v.x + v.y * v.y;
  #pragma unroll
  for (int off = 32; off > 0; off >>= 1) ss += __shfl_down(ss, off, 64);
  if (lane == 0) *dst = ss;
}

// ---------------- kernel 2: MFMA bf16 GEMM -> c, diagonal-skew-stored ----------------
// c_sk[s][t][l] = c(row 64s+l, col j) with t = j + l
__device__ __forceinline__ v8s pack_bf16x8(float4 a, float4 b) {
  union { unsigned int u[4]; v8s v; } r;
  union { __hip_bfloat162 h; unsigned int u; } t;
  t.h = __float22bfloat162_rn(make_float2(a.x, a.y)); r.u[0] = t.u;
  t.h = __float22bfloat162_rn(make_float2(a.z, a.w)); r.u[1] = t.u;
  t.h = __float22bfloat162_rn(make_float2(b.x, b.y)); r.u[2] = t.u;
  t.h = __float22bfloat162_rn(make_float2(b.z, b.w)); r.u[3] = t.u;
  return r.v;
}

__global__ __launch_bounds__(256) void kgemm(
    const float* __restrict__ kern, const float* __restrict__ xx,
    const float* __restrict__ x2, const float* __restrict__ k2,
    float* __restrict__ c_sk) {
  __shared__ float ctile[64 * 64];   // [n=x-col][m-swizzled]
  const int T = threadIdx.x;
  const int w = T >> 6;
  const int lane = T & 63;
  const int lo = lane & 15;
  const int hi = lane >> 4;
  const int i0 = blockIdx.x * 64;    // DTW columns (x rows)
  const int s  = blockIdx.y;         // strip
  const int kr0 = s * 64;

  v4f acc[4] = {};
  #pragma unroll
  for (int ks = 0; ks < 4; ks++) {
    const int k = ks * 32 + hi * 8;
    const float* bp = xx + (size_t)(i0 + w * 16 + lo) * DIMV + k;
    v8s bf = pack_bf16x8(*(const float4*)bp, *(const float4*)(bp + 4));
    #pragma unroll
    for (int rt = 0; rt < 4; rt++) {
      const float* ap = kern + (size_t)(kr0 + rt * 16 + lo) * DIMV + k;
      v8s af = pack_bf16x8(*(const float4*)ap, *(const float4*)(ap + 4));
      acc[rt] = __builtin_amdgcn_mfma_f32_16x16x32_bf16(af, bf, acc[rt], 0, 0, 0);
    }
  }
  const float x2v = x2[i0 + w * 16 + lo];
  const int n_local = w * 16 + lo;
  #pragma unroll
  for (int rt = 0; rt < 4; rt++) {
    float4 k2f = *(const float4*)&k2[kr0 + rt * 16 + hi * 4];
    #pragma unroll
    for (int q = 0; q < 4; q++) {
      const int m_local = rt * 16 + hi * 4 + q;
      float cval = fmaxf((&k2f.x)[q] + x2v - 2.f * acc[rt][q], 0.f);
      ctile[n_local * 64 + ((m_local + 2 * n_local) & 63)] = cval;
    }
  }
  __syncthreads();
  // skew-scatter: skewed row t = i0 + tt; lane l = kernel-row; contiguous 256B per tt
  float* ob = c_sk + (size_t)s * SSTRIDE + (size_t)i0 * 64 + lane;
  #pragma unroll
  for (int q = 0; q < 32; q++) {
    int tt = w + q * 4;              // local skewed row in [0,126]
    int di = tt - lane;
    if (tt <= 126 && di >= 0 && di < 64)
      ob[tt * 64] = ctile[di * 64 + ((lane + 2 * di) & 63)];
  }
}

// ---------------- kernel 3: wavefront DP, producer/consumer waves ----------------
__device__ __forceinline__ float dpp_wave_shr1(float oldv, float src) {
  return __int_as_float(__builtin_amdgcn_update_dpp(
      __float_as_int(oldv), __float_as_int(src), 0x138, 0xF, 0xF, false));
}
__device__ __forceinline__ float dpp_wave_rol1(float src) {
  return __int_as_float(__builtin_amdgcn_update_dpp(
      __float_as_int(src), __float_as_int(src), 0x134, 0xF, 0xF, false));
}
__device__ __forceinline__ float dpp_wave_shl1(float oldv, float src) {
  return __int_as_float(__builtin_amdgcn_update_dpp(
      __float_as_int(oldv), __float_as_int(src), 0x130, 0xF, 0xF, false));
}

__device__ __forceinline__ void issue_chunk(const float* cstrip, float* lslot, int c, int lane) {
  const float* g = cstrip + (size_t)c * 4096 + lane * 4;  // 16 B per lane
  #pragma unroll
  for (int i = 0; i < 16; i++) {
    __builtin_amdgcn_global_load_lds(
        (const __attribute__((address_space(1))) void*)(g + i * 256),
        (__attribute__((address_space(3))) void*)(lslot + i * 256),
        16, 0, 0);
  }
}

__global__ __launch_bounds__(128) void kdp(
    const float* __restrict__ c_sk, float* __restrict__ bound,
    int* __restrict__ flags, float* __restrict__ out) {
  __shared__ float lbuf[2 * 64 * 64];   // 2 slots x 64 steps x 64 floats = 32 KB
  const int s = blockIdx.x;
  const int wv = threadIdx.x >> 6;      // 0 = DP consumer, 1 = streamer
  const int lane = threadIdx.x & 63;
  const float* cstrip = c_sk + (size_t)s * SSTRIDE;
  float* bout = bound + (size_t)s * IL;
  const float* bin = bound + (size_t)(s - 1) * IL;

  if (wv == 1) issue_chunk(cstrip, lbuf, 0, lane);
  __syncthreads();   // producer drains chunk 0 (vmcnt0 in barrier); consumer idle

  // consumer state (producer carries dead copies)
  float Bv = INF, bb1 = INF;
  int fchk = 0x7fffffff;
  if (wv == 0 && s > 0) {
    int f;
    do { f = __hip_atomic_load(&flags[s - 1], __ATOMIC_RELAXED, __HIP_MEMORY_SCOPE_AGENT); } while (f < 128);
    Bv  = __hip_atomic_load(&bin[lane],      __ATOMIC_RELAXED, __HIP_MEMORY_SCOPE_AGENT);
    bb1 = __hip_atomic_load(&bin[64 + lane], __ATOMIC_RELAXED, __HIP_MEMORY_SCOPE_AGENT);
    fchk = f;
  }
  float Dcur = (s == 0 && lane == 0) ? 0.f : INF;  // doubles as D-left
  float Dul = INF;
  float Bout = INF;

  for (int W = 0; W < NW; W++) {
    if (wv == 1) {
      if (W < NW - 1) issue_chunk(cstrip, lbuf + ((W + 1) & 1) * 4096, W + 1, lane);
    } else {
      const int t0 = W * 64;
      float bb2 = INF;
      int fnew = fchk;
      if (s > 0 && W < NW - 1) {
        int need = t0 + 128; if (need > IL) need = IL;
        if (fchk < need) {  // slow path: pipeline fill only
          int f;
          do { f = __hip_atomic_load(&flags[s - 1], __ATOMIC_RELAXED, __HIP_MEMORY_SCOPE_AGENT); } while (f < need);
          int rb = t0 + 64; if (rb > IL - 64) rb = IL - 64;
          bb1 = __hip_atomic_load(&bin[rb + lane], __ATOMIC_RELAXED, __HIP_MEMORY_SCOPE_AGENT);
          fchk = f;
        }
        int nb = t0 + 128; if (nb > IL - 64) nb = IL - 64;
        bb2  = __hip_atomic_load(&bin[nb + lane], __ATOMIC_RELAXED, __HIP_MEMORY_SCOPE_AGENT);
        fnew = __hip_atomic_load(&flags[s - 1],   __ATOMIC_RELAXED, __HIP_MEMORY_SCOPE_AGENT);
      }
      // batch LDS reads for this chunk (2-way bank alias = free)
      const float* lc = lbuf + (W & 1) * 4096 + lane;
      float cvv[64];
      #pragma unroll
      for (int tt = 0; tt < 64; tt++) cvv[tt] = lc[tt * 64];
      if (W >= 1 && W <= 127) {
        #pragma unroll
        for (int tt = 0; tt < 64; tt++) {
          float Dup = dpp_wave_shr1(Bv, Dcur);   // D[r-1][j]; lane0 from feed
          Bv = dpp_wave_rol1(Bv);
          float Dnew = cvv[tt] + fminf(fminf(Dul, Dup), Dcur);
          Dul = Dup;
          Dcur = Dnew;
          Bout = dpp_wave_shl1(Dcur, Bout);      // lane63 injects bottom-row value
        }
      } else {
        #pragma unroll
        for (int tt = 0; tt < 64; tt++) {
          const int t = t0 + tt;
          float Dup = dpp_wave_shr1(Bv, Dcur);
          Bv = dpp_wave_rol1(Bv);
          float Dnew = cvv[tt] + fminf(fminf(Dul, Dup), Dcur);
          const bool alo = (t >= lane);          // j >= 0
          const bool ahi = (t - lane < IL);      // j < IL
          if (alo) Dul = Dup;
          if (alo && ahi) Dcur = Dnew;
          Bout = dpp_wave_shl1(Dcur, Bout);
        }
      }
      if (s < NS - 1) {
        const int j = t0 + lane - 63;
        if (j >= 0 && j < IL)
          __hip_atomic_store(&bout[j], Bout, __ATOMIC_RELAXED, __HIP_MEMORY_SCOPE_AGENT);
        if (W >= 1 && lane == 0)
          __hip_atomic_store(&flags[s], 64 * (W - 1) + 1, __ATOMIC_RELAXED, __HIP_MEMORY_SCOPE_AGENT);
      }
      if (s > 0) { Bv = bb1; bb1 = bb2; fchk = fnew; }
    }
    __syncthreads();   // hands next slot to consumer; drains producer loads
  }
  if (wv == 0) {
    if (s < NS - 1) {
      __threadfence();
      if (lane == 0)
        __hip_atomic_store(&flags[s], IL, __ATOMIC_RELAXED, __HIP_MEMORY_SCOPE_AGENT);
    }
    if (s == NS - 1 && lane == 63) out[0] = Dcur;  // D[K-1][I-1] == optimal path sum
  }
}

extern "C" void kernel_launch(void* const* d_in, const int* in_sizes, int n_in,
                              void* d_out, int out_size, void* d_ws, size_t ws_size,
                              hipStream_t stream) {
  const float* kern = (const float*)d_in[0]; // (1024,128)
  const float* xx   = (const float*)d_in[1]; // (8192,128)
  char* ws = (char*)d_ws;
  const size_t OFF_X2 = (size_t)NS * SSTRIDE * 4;       // c_sk: ~34.1 MB
  const size_t OFF_K2 = OFF_X2 + (size_t)IL * 4;
  const size_t OFF_BD = OFF_K2 + (size_t)KL * 4;
  const size_t OFF_FL = OFF_BD + (size_t)NS * IL * 4;
  float* c_sk  = (float*)ws;
  float* x2    = (float*)(ws + OFF_X2);
  float* k2    = (float*)(ws + OFF_K2);
  float* bnd   = (float*)(ws + OFF_BD);
  int*   flags = (int*)(ws + OFF_FL);

  knorms<<<(IL + KL) / 4, 256, 0, stream>>>(kern, xx, x2, k2, flags);
  kgemm<<<dim3(IL / 64, NS), 256, 0, stream>>>(kern, xx, x2, k2, c_sk);
  kdp<<<NS, 128, 0, stream>>>(c_sk, bnd, flags, (float*)d_out);
}

// Round 6
// 454.352 us; speedup vs baseline: 1.4264x; 1.1160x over previous
//
#include <hip/hip_runtime.h>
#include <hip/hip_bf16.h>

#define KL 1024
#define IL 8192
#define DIMV 128
#define NS 16               // row strips of 64 (1 row per lane)
#define TROWS 8320          // skewed rows allocated per strip (used: t <= 8255)
#define SSTRIDE (TROWS*64)  // floats per strip in c_sk
#define NW 129              // 129 chunks x 64 = 8256 DP steps
#define CUSH 6              // start cushion in 64-col blocks
#define INF __builtin_inff()

typedef __attribute__((ext_vector_type(8))) short v8s;   // bf16x8 MFMA A/B frag
typedef __attribute__((ext_vector_type(4))) float v4f;   // MFMA C/D frag

// ---------------- kernel 1: squared row norms + zero flags ----------------
__global__ __launch_bounds__(256) void knorms(
    const float* __restrict__ kern, const float* __restrict__ xx,
    float* __restrict__ x2, float* __restrict__ k2, int* __restrict__ flags) {
  if (blockIdx.x == 0 && threadIdx.x < NS) flags[threadIdx.x] = 0;
  const int lane = threadIdx.x & 63;
  const int row = blockIdx.x * 4 + (threadIdx.x >> 6);
  const float* src;
  float* dst;
  if (row < IL) { src = xx + (size_t)row * DIMV; dst = x2 + row; }
  else          { src = kern + (size_t)(row - IL) * DIMV; dst = k2 + (row - IL); }
  float2 v = *(const float2*)(src + lane * 2);
  float ss = v.x * v.x + v.y * v.y;
  #pragma unroll
  for (int off = 32; off > 0; off >>= 1) ss += __shfl_down(ss, off, 64);
  if (lane == 0) *dst = ss;
}

// ---------------- kernel 2: MFMA bf16 GEMM -> c, diagonal-skew-stored ----------------
// c_sk[s][t][l] = c(row 64s+l, col j) with t = j + l
__device__ __forceinline__ v8s pack_bf16x8(float4 a, float4 b) {
  union { unsigned int u[4]; v8s v; } r;
  union { __hip_bfloat162 h; unsigned int u; } t;
  t.h = __float22bfloat162_rn(make_float2(a.x, a.y)); r.u[0] = t.u;
  t.h = __float22bfloat162_rn(make_float2(a.z, a.w)); r.u[1] = t.u;
  t.h = __float22bfloat162_rn(make_float2(b.x, b.y)); r.u[2] = t.u;
  t.h = __float22bfloat162_rn(make_float2(b.z, b.w)); r.u[3] = t.u;
  return r.v;
}

__global__ __launch_bounds__(256) void kgemm(
    const float* __restrict__ kern, const float* __restrict__ xx,
    const float* __restrict__ x2, const float* __restrict__ k2,
    float* __restrict__ c_sk) {
  __shared__ float ctile[64 * 64];   // [n=x-col][m-swizzled]
  const int T = threadIdx.x;
  const int w = T >> 6;
  const int lane = T & 63;
  const int lo = lane & 15;
  const int hi = lane >> 4;
  const int i0 = blockIdx.x * 64;    // DTW columns (x rows)
  const int s  = blockIdx.y;         // strip
  const int kr0 = s * 64;

  v4f acc[4] = {};
  #pragma unroll
  for (int ks = 0; ks < 4; ks++) {
    const int k = ks * 32 + hi * 8;
    const float* bp = xx + (size_t)(i0 + w * 16 + lo) * DIMV + k;
    v8s bf = pack_bf16x8(*(const float4*)bp, *(const float4*)(bp + 4));
    #pragma unroll
    for (int rt = 0; rt < 4; rt++) {
      const float* ap = kern + (size_t)(kr0 + rt * 16 + lo) * DIMV + k;
      v8s af = pack_bf16x8(*(const float4*)ap, *(const float4*)(ap + 4));
      acc[rt] = __builtin_amdgcn_mfma_f32_16x16x32_bf16(af, bf, acc[rt], 0, 0, 0);
    }
  }
  const float x2v = x2[i0 + w * 16 + lo];
  const int n_local = w * 16 + lo;
  #pragma unroll
  for (int rt = 0; rt < 4; rt++) {
    float4 k2f = *(const float4*)&k2[kr0 + rt * 16 + hi * 4];
    #pragma unroll
    for (int q = 0; q < 4; q++) {
      const int m_local = rt * 16 + hi * 4 + q;
      float cval = fmaxf((&k2f.x)[q] + x2v - 2.f * acc[rt][q], 0.f);
      ctile[n_local * 64 + ((m_local + 2 * n_local) & 63)] = cval;
    }
  }
  __syncthreads();
  // skew-scatter: skewed row t = i0 + tt; lane l = kernel-row; contiguous 256B per tt
  float* ob = c_sk + (size_t)s * SSTRIDE + (size_t)i0 * 64 + lane;
  #pragma unroll
  for (int q = 0; q < 32; q++) {
    int tt = w + q * 4;              // local skewed row in [0,126]
    int di = tt - lane;
    if (tt <= 126 && di >= 0 && di < 64)
      ob[tt * 64] = ctile[di * 64 + ((lane + 2 * di) & 63)];
  }
}

// ---------------- kernel 3: wavefront DP, 3 waves: DP / c-stream / sync ----------------
__device__ __forceinline__ float dpp_wave_shr1(float oldv, float src) {
  return __int_as_float(__builtin_amdgcn_update_dpp(
      __float_as_int(oldv), __float_as_int(src), 0x138, 0xF, 0xF, false));
}
__device__ __forceinline__ float dpp_wave_rol1(float src) {
  return __int_as_float(__builtin_amdgcn_update_dpp(
      __float_as_int(src), __float_as_int(src), 0x134, 0xF, 0xF, false));
}
__device__ __forceinline__ float dpp_wave_shl1(float oldv, float src) {
  return __int_as_float(__builtin_amdgcn_update_dpp(
      __float_as_int(oldv), __float_as_int(src), 0x130, 0xF, 0xF, false));
}

__device__ __forceinline__ void issue_chunk(const float* cstrip, float* lslot, int c, int lane) {
  const float* g = cstrip + (size_t)c * 4096 + lane * 4;  // 16 B per lane
  #pragma unroll
  for (int i = 0; i < 16; i++) {
    __builtin_amdgcn_global_load_lds(
        (const __attribute__((address_space(1))) void*)(g + i * 256),
        (__attribute__((address_space(3))) void*)(lslot + i * 256),
        16, 0, 0);
  }
}

__global__ __launch_bounds__(192) void kdp(
    const float* __restrict__ c_sk, float* __restrict__ bound,
    int* __restrict__ flags, float* __restrict__ out) {
  __shared__ float lbuf[2 * 4096];   // c double-buffer (32 KB)
  __shared__ float feed[4 * 64];     // inbound boundary ring
  __shared__ float bexp[2 * 64];     // outbound boundary double-buffer
  const int s = blockIdx.x;
  const int wv = threadIdx.x >> 6;   // 0=DP, 1=c-streamer, 2=sync
  const int lane = threadIdx.x & 63;
  const float* cstrip = c_sk + (size_t)s * SSTRIDE;
  float* bout = bound + (size_t)s * IL;
  const float* bin = bound + (size_t)(s - 1) * IL;

  int fchk = 0;
  if (wv == 1) issue_chunk(cstrip, lbuf, 0, lane);
  if (wv == 2) {
    if (s > 0) {
      int f;
      do { f = __hip_atomic_load(&flags[s - 1], __ATOMIC_RELAXED, __HIP_MEMORY_SCOPE_AGENT); } while (f < 64 * CUSH);
      fchk = f;
      feed[lane]      = __hip_atomic_load(&bin[lane],      __ATOMIC_RELAXED, __HIP_MEMORY_SCOPE_AGENT);
      feed[64 + lane] = __hip_atomic_load(&bin[64 + lane], __ATOMIC_RELAXED, __HIP_MEMORY_SCOPE_AGENT);
    } else {
      feed[lane] = INF; feed[64 + lane] = INF; feed[128 + lane] = INF; feed[192 + lane] = INF;
    }
  }
  __syncthreads();

  float Dcur = (s == 0 && lane == 0) ? 0.f : INF;  // doubles as D-left
  float Dul = INF;
  float Bout = INF;

  for (int W = 0; W < NW; W++) {
    if (wv == 1) {
      if (W + 1 < NW) issue_chunk(cstrip, lbuf + ((W + 1) & 1) * 4096, W + 1, lane);
    } else if (wv == 2) {
      if (s > 0 && W + 2 <= 127) {
        // stage feed for DP block W+2 (cols [64(W+2), 64(W+2)+64))
        const int need = 64 * (W + 2) + 64;
        if (fchk < need) {   // pipeline fill only (cushion covers steady state)
          int f;
          do { f = __hip_atomic_load(&flags[s - 1], __ATOMIC_RELAXED, __HIP_MEMORY_SCOPE_AGENT); } while (f < need);
          fchk = f;
        }
        feed[((W + 2) & 3) * 64 + lane] =
            __hip_atomic_load(&bin[64 * (W + 2) + lane], __ATOMIC_RELAXED, __HIP_MEMORY_SCOPE_AGENT);
      }
      if (s < NS - 1 && W >= 1) {
        // export DP's block W-1 boundary snapshot; then fence + publish
        float bv = bexp[((W - 1) & 1) * 64 + lane];
        const int j = 64 * (W - 1) + lane - 63;
        if (j >= 0)
          __hip_atomic_store(&bout[j], bv, __ATOMIC_RELAXED, __HIP_MEMORY_SCOPE_AGENT);
        __threadfence();
        if (lane == 0)
          __hip_atomic_store(&flags[s], 64 * (W - 1) + 1, __ATOMIC_RELAXED, __HIP_MEMORY_SCOPE_AGENT);
      }
    } else {
      // ---- DP wave: pure LDS + DPP + VALU ----
      const float* lc = lbuf + (W & 1) * 4096 + lane;
      float Bv = feed[(W & 3) * 64 + lane];
      float cva[8], cvb[8];
      #pragma unroll
      for (int i = 0; i < 8; i++) cva[i] = lc[i * 64];
      if (W >= 1 && W <= 127) {
        #pragma unroll
        for (int g = 0; g < 8; g++) {
          float* cur = (g & 1) ? cvb : cva;
          float* nxt = (g & 1) ? cva : cvb;
          if (g < 7) {
            #pragma unroll
            for (int i = 0; i < 8; i++) nxt[i] = lc[((g + 1) * 8 + i) * 64];
          }
          #pragma unroll
          for (int i = 0; i < 8; i++) {
            float Dup = dpp_wave_shr1(Bv, Dcur);  // dep chain: dpp -> fmin -> add
            float m1 = fminf(Dul, Dcur);          // parallel with dpp
            Bv = dpp_wave_rol1(Bv);
            Dcur = cur[i] + fminf(m1, Dup);
            Dul = Dup;
            Bout = dpp_wave_shl1(Dcur, Bout);
          }
        }
      } else {
        const int t0 = W * 64;
        #pragma unroll
        for (int g = 0; g < 8; g++) {
          float* cur = (g & 1) ? cvb : cva;
          float* nxt = (g & 1) ? cva : cvb;
          if (g < 7) {
            #pragma unroll
            for (int i = 0; i < 8; i++) nxt[i] = lc[((g + 1) * 8 + i) * 64];
          }
          #pragma unroll
          for (int i = 0; i < 8; i++) {
            const int t = t0 + g * 8 + i;
            float Dup = dpp_wave_shr1(Bv, Dcur);
            float m1 = fminf(Dul, Dcur);
            Bv = dpp_wave_rol1(Bv);
            float Dnew = cur[i] + fminf(m1, Dup);
            const bool alo = (t >= lane);          // j >= 0
            const bool ahi = (t - lane < IL);      // j < IL
            if (alo) Dul = Dup;
            if (alo && ahi) Dcur = Dnew;
            Bout = dpp_wave_shl1(Dcur, Bout);
          }
        }
      }
      bexp[(W & 1) * 64 + lane] = Bout;  // snapshot for sync wave to export next iter
    }
    __syncthreads();
  }
  // epilogue: export final block's boundary + full publish
  if (wv == 2 && s < NS - 1) {
    float bv = bexp[((NW - 1) & 1) * 64 + lane];
    const int j = 64 * (NW - 1) + lane - 63;
    if (j >= 0 && j < IL)
      __hip_atomic_store(&bout[j], bv, __ATOMIC_RELAXED, __HIP_MEMORY_SCOPE_AGENT);
    __threadfence();
    if (lane == 0)
      __hip_atomic_store(&flags[s], IL, __ATOMIC_RELAXED, __HIP_MEMORY_SCOPE_AGENT);
  }
  if (wv == 0 && s == NS - 1 && lane == 63) out[0] = Dcur;  // D[K-1][I-1] == path sum
}

extern "C" void kernel_launch(void* const* d_in, const int* in_sizes, int n_in,
                              void* d_out, int out_size, void* d_ws, size_t ws_size,
                              hipStream_t stream) {
  const float* kern = (const float*)d_in[0]; // (1024,128)
  const float* xx   = (const float*)d_in[1]; // (8192,128)
  char* ws = (char*)d_ws;
  const size_t OFF_X2 = (size_t)NS * SSTRIDE * 4;       // c_sk: ~34.1 MB
  const size_t OFF_K2 = OFF_X2 + (size_t)IL * 4;
  const size_t OFF_BD = OFF_K2 + (size_t)KL * 4;
  const size_t OFF_FL = OFF_BD + (size_t)NS * IL * 4;
  float* c_sk  = (float*)ws;
  float* x2    = (float*)(ws + OFF_X2);
  float* k2    = (float*)(ws + OFF_K2);
  float* bnd   = (float*)(ws + OFF_BD);
  int*   flags = (int*)(ws + OFF_FL);

  knorms<<<(IL + KL) / 4, 256, 0, stream>>>(kern, xx, x2, k2, flags);
  kgemm<<<dim3(IL / 64, NS), 256, 0, stream>>>(kern, xx, x2, k2, c_sk);
  kdp<<<NS, 192, 0, stream>>>(c_sk, bnd, flags, (float*)d_out);
}

// Round 8
// 405.256 us; speedup vs baseline: 1.5992x; 1.1211x over previous
//
#include <hip/hip_runtime.h>
#include <hip/hip_bf16.h>

typedef unsigned short ushort_t;
typedef unsigned int uint_t;

#define KL 1024
#define IL 8192
#define DIMV 128
#define NS 16
#define NB 258               // 32-col blocks per strip (258*32 = 8256 skewed steps)
#define NIT 269              // covers wave3 (i<=266) + export (267) + publish (268)
#define SSH (8256*64)        // ushorts per strip of c_h (fp16, pair-packed)
#define GATE 416             // cross-wg start cushion: 13 blocks * 32 cols
#define INF __builtin_inff()

typedef __attribute__((ext_vector_type(8))) short v8s;   // bf16x8 MFMA A/B frag
typedef __attribute__((ext_vector_type(4))) float v4f;   // MFMA C/D frag

// ---------------- kernel 1: squared row norms + zero flags ----------------
__global__ __launch_bounds__(256) void knorms(
    const float* __restrict__ kern, const float* __restrict__ xx,
    float* __restrict__ x2, float* __restrict__ k2, int* __restrict__ flags) {
  if (blockIdx.x == 0 && threadIdx.x < NS) flags[threadIdx.x] = 0;
  const int lane = threadIdx.x & 63;
  const int row = blockIdx.x * 4 + (threadIdx.x >> 6);
  const float* src;
  float* dst;
  if (row < IL) { src = xx + (size_t)row * DIMV; dst = x2 + row; }
  else          { src = kern + (size_t)(row - IL) * DIMV; dst = k2 + (row - IL); }
  float2 v = *(const float2*)(src + lane * 2);
  float ss = v.x * v.x + v.y * v.y;
  #pragma unroll
  for (int off = 32; off > 0; off >>= 1) ss += __shfl_down(ss, off, 64);
  if (lane == 0) *dst = ss;
}

// ---------------- kernel 2: MFMA bf16 GEMM -> c (fp16), diagonal-skew-stored ----
// c_h[s][tp][l] packs (c at t=2tp, t=2tp+1) for row 64s+l, t = col + l
__device__ __forceinline__ v8s pack_bf16x8(float4 a, float4 b) {
  union { unsigned int u[4]; v8s v; } r;
  union { __hip_bfloat162 h; unsigned int u; } t;
  t.h = __float22bfloat162_rn(make_float2(a.x, a.y)); r.u[0] = t.u;
  t.h = __float22bfloat162_rn(make_float2(a.z, a.w)); r.u[1] = t.u;
  t.h = __float22bfloat162_rn(make_float2(b.x, b.y)); r.u[2] = t.u;
  t.h = __float22bfloat162_rn(make_float2(b.z, b.w)); r.u[3] = t.u;
  return r.v;
}

__global__ __launch_bounds__(256) void kgemm(
    const float* __restrict__ kern, const float* __restrict__ xx,
    const float* __restrict__ x2, const float* __restrict__ k2,
    ushort_t* __restrict__ c_h) {
  __shared__ float ctile[64 * 64];   // [n=x-col][m-swizzled]
  const int T = threadIdx.x;
  const int w = T >> 6;
  const int lane = T & 63;
  const int lo = lane & 15;
  const int hi = lane >> 4;
  const int i0 = blockIdx.x * 64;    // DTW columns (x rows)
  const int s  = blockIdx.y;         // strip
  const int kr0 = s * 64;

  v4f acc[4] = {};
  #pragma unroll
  for (int ks = 0; ks < 4; ks++) {
    const int k = ks * 32 + hi * 8;
    const float* bp = xx + (size_t)(i0 + w * 16 + lo) * DIMV + k;
    v8s bf = pack_bf16x8(*(const float4*)bp, *(const float4*)(bp + 4));
    #pragma unroll
    for (int rt = 0; rt < 4; rt++) {
      const float* ap = kern + (size_t)(kr0 + rt * 16 + lo) * DIMV + k;
      v8s af = pack_bf16x8(*(const float4*)ap, *(const float4*)(ap + 4));
      acc[rt] = __builtin_amdgcn_mfma_f32_16x16x32_bf16(af, bf, acc[rt], 0, 0, 0);
    }
  }
  const float x2v = x2[i0 + w * 16 + lo];
  const int n_local = w * 16 + lo;
  #pragma unroll
  for (int rt = 0; rt < 4; rt++) {
    float4 k2f = *(const float4*)&k2[kr0 + rt * 16 + hi * 4];
    #pragma unroll
    for (int q = 0; q < 4; q++) {
      const int m_local = rt * 16 + hi * 4 + q;
      float cval = fmaxf((&k2f.x)[q] + x2v - 2.f * acc[rt][q], 0.f);
      ctile[n_local * 64 + ((m_local + 2 * n_local) & 63)] = cval;
    }
  }
  __syncthreads();
  // skew-scatter as fp16 pairs: element (t = i0+tt, lane=dk)
  _Float16* ob = (_Float16*)(c_h + (size_t)s * SSH);
  #pragma unroll
  for (int q = 0; q < 32; q++) {
    int tt = w + q * 4;              // local skewed row in [0,126]
    int di = tt - lane;
    if (tt <= 126 && di >= 0 && di < 64) {
      int t = i0 + tt;
      ob[((size_t)(t >> 1) * 64 + lane) * 2 + (t & 1)] =
          (_Float16)ctile[di * 64 + ((lane + 2 * di) & 63)];
    }
  }
}

// ---------------- kernel 3: 4 strips per workgroup, 6 waves, lag-3 pipeline ----------------
__device__ __forceinline__ float dpp_wave_shr1(float oldv, float src) {
  return __int_as_float(__builtin_amdgcn_update_dpp(
      __float_as_int(oldv), __float_as_int(src), 0x138, 0xF, 0xF, false));
}
__device__ __forceinline__ float dpp_wave_rol1(float src) {
  return __int_as_float(__builtin_amdgcn_update_dpp(
      __float_as_int(src), __float_as_int(src), 0x134, 0xF, 0xF, false));
}
__device__ __forceinline__ float dpp_wave_shl1(float oldv, float src) {
  return __int_as_float(__builtin_amdgcn_update_dpp(
      __float_as_int(oldv), __float_as_int(src), 0x130, 0xF, 0xF, false));
}

__global__ __launch_bounds__(384) void kdp(
    const ushort_t* __restrict__ c_h, float* __restrict__ bound,
    int* __restrict__ flags, float* __restrict__ out) {
  __shared__ uint_t cbuf[4 * 2 * 1024];   // strip k, slot p: (k*2+p)*1024 uints (32 KB)
  __shared__ float ring[4 * 4 * 32];      // wave k out-ring: ring + k*128; slot q = cols 32q..32q+31
  __shared__ float feed[4 * 32];          // sync -> wave0 feed ring
  const int g = blockIdx.x;
  const int wv = threadIdx.x >> 6;        // 0..3 DP, 4 streamer, 5 sync
  const int lane = threadIdx.x & 63;
  const int sb = g * 4;

  float Dcur = INF, Dul = INF, Bout = INF;
  int fchk = 0, fpend = 0;
  float rfeed = INF;
  const float* bin = bound + (size_t)(sb > 0 ? sb - 1 : 0) * IL;
  float* bout3 = bound + (size_t)(sb + 3) * IL;

  // ---- pre-loop staging ----
  if (wv == 4) {
    // stage strip 0 block 0 -> slot 0
    const char* gs = (const char*)(c_h + (size_t)sb * SSH);
    uint_t* dst = cbuf;
    #pragma unroll
    for (int q = 0; q < 4; q++)
      __builtin_amdgcn_global_load_lds(
          (const __attribute__((address_space(1))) void*)(gs + (size_t)q * 1024 + lane * 16),
          (__attribute__((address_space(3))) void*)(dst + q * 256 + lane * 4), 16, 0, 0);
  } else if (wv == 5) {
    if (g > 0) {
      int f;
      do { f = __hip_atomic_load(&flags[sb - 1], __ATOMIC_RELAXED, __HIP_MEMORY_SCOPE_AGENT); } while (f < GATE);
      fchk = f; fpend = f;
      if (lane < 32) {
        feed[lane]      = __hip_atomic_load(&bin[lane],      __ATOMIC_RELAXED, __HIP_MEMORY_SCOPE_AGENT);
        feed[32 + lane] = __hip_atomic_load(&bin[32 + lane], __ATOMIC_RELAXED, __HIP_MEMORY_SCOPE_AGENT);
        rfeed           = __hip_atomic_load(&bin[64 + lane], __ATOMIC_RELAXED, __HIP_MEMORY_SCOPE_AGENT);
      }
    } else {
      if (lane < 32) { feed[lane] = INF; feed[32+lane] = INF; feed[64+lane] = INF; feed[96+lane] = INF; }
    }
  } else if (wv < 4) {
    if (g == 0 && wv == 0 && lane == 0) Dcur = 0.f;
  }
  __syncthreads();

  for (int i = 0; i < NIT; i++) {
    if (wv < 4) {
      // ---- DP wave k = wv, strip sb+k, block W = i - 3k (lag 3) ----
      const int W = i - 3 * wv;
      if (W >= 0 && W < NB) {
        const uint_t* lc = cbuf + (wv * 2 + (W & 1)) * 1024 + lane;
        uint_t lv[16];
        #pragma unroll
        for (int tp = 0; tp < 16; tp++) lv[tp] = lc[tp * 64];
        float Bv = (wv == 0) ? feed[(W & 3) * 32 + (lane & 31)]
                             : ring[(wv - 1) * 128 + (W & 3) * 32 + (lane & 31)];
        float cvv[32];
        #pragma unroll
        for (int tp = 0; tp < 16; tp++) {
          union { uint_t u; _Float16 h[2]; } cu; cu.u = lv[tp];
          cvv[2 * tp]     = (float)cu.h[0];
          cvv[2 * tp + 1] = (float)cu.h[1];
        }
        if (W >= 2 && W < 256) {
          #pragma unroll
          for (int tt = 0; tt < 32; tt++) {
            float Dup = dpp_wave_shr1(Bv, Dcur);   // lane0 <- feed; lane m <- Dcur[m-1]
            float m1 = fminf(Dul, Dcur);           // parallel with dpp
            Bv = dpp_wave_rol1(Bv);
            Dcur = cvv[tt] + fminf(m1, Dup);
            Dul = Dup;
            Bout = dpp_wave_shl1(Dcur, Bout);      // lane63 injects bottom-row value
          }
        } else {
          const int t0 = W * 32;
          #pragma unroll
          for (int tt = 0; tt < 32; tt++) {
            const int t = t0 + tt;
            float Dup = dpp_wave_shr1(Bv, Dcur);
            float m1 = fminf(Dul, Dcur);
            Bv = dpp_wave_rol1(Bv);
            float Dnew = cvv[tt] + fminf(m1, Dup);
            const bool alo = (t >= lane);          // j >= 0
            const bool ahi = (t - lane < IL);      // j < IL
            if (alo) Dul = Dup;
            if (alo && ahi) Dcur = Dnew;
            Bout = dpp_wave_shl1(Dcur, Bout);
          }
        }
        // ring write (corrected): after block W, lane63 holds col 32(W-1) -> slot W-1 pos 0;
        // lanes 32..62 hold cols 32(W-2)+(l-31) -> slot W-2 pos l-31
        if (lane >= 32) {
          const int slot = (lane == 63) ? (W - 1) : (W - 2);
          if (slot >= 0)
            ring[wv * 128 + ((slot & 3) << 5) + ((lane + 1) & 31)] = Bout;
        }
      }
    } else if (wv == 4) {
      // ---- streamer: stage strip k's block B = i+1-3k into slot (B&1) ----
      #pragma unroll
      for (int k = 0; k < 4; k++) {
        const int B = i + 1 - 3 * k;
        if (B >= 0 && B < NB) {
          const char* gs = (const char*)(c_h + (size_t)(sb + k) * SSH) + (size_t)B * 4096;
          uint_t* dst = cbuf + (k * 2 + (B & 1)) * 1024;
          #pragma unroll
          for (int q = 0; q < 4; q++)
            __builtin_amdgcn_global_load_lds(
                (const __attribute__((address_space(1))) void*)(gs + (size_t)q * 1024 + lane * 16),
                (__attribute__((address_space(3))) void*)(dst + q * 256 + lane * 4), 16, 0, 0);
        }
      }
    } else {
      // ---- sync wave ----
      if (g > 0) {
        if (fpend > fchk) fchk = fpend;           // consume last iter's flag load (drained)
        const int Fw = i + 2;                     // ds_write feed loaded last iter
        if (Fw >= 2 && Fw <= 255 && lane < 32) feed[(Fw & 3) * 32 + lane] = rfeed;
        const int Fl = i + 3;                     // issue next feed load
        if (Fl <= 255) {
          const int need = 32 * (Fl + 1);
          if (fchk < need) {                      // rare (cushion + tracking cover steady state)
            int f;
            do { f = __hip_atomic_load(&flags[sb - 1], __ATOMIC_RELAXED, __HIP_MEMORY_SCOPE_AGENT); } while (f < need);
            fchk = f;
          }
          if (lane < 32)
            rfeed = __hip_atomic_load(&bin[32 * Fl + lane], __ATOMIC_RELAXED, __HIP_MEMORY_SCOPE_AGENT);
        }
        fpend = __hip_atomic_load(&flags[sb - 1], __ATOMIC_RELAXED, __HIP_MEMORY_SCOPE_AGENT);
      }
      if (g < 3) {
        const int E = i - 12;                     // export wave3's boundary block E (slot done at E+11)
        if (E >= 0 && E < 256 && lane < 32) {
          float bv2 = ring[3 * 128 + (E & 3) * 32 + lane];
          __hip_atomic_store(&bout3[32 * E + lane], bv2, __ATOMIC_RELAXED, __HIP_MEMORY_SCOPE_AGENT);
        }
        const int Ep = i - 13;                    // publish E-1's export (drained at prior barrier)
        if (Ep >= 0 && Ep < 256 && lane == 0)
          __hip_atomic_store(&flags[sb + 3], 32 * Ep + 32, __ATOMIC_RELAXED, __HIP_MEMORY_SCOPE_AGENT);
      }
    }
    __syncthreads();
  }
  if (g == 3 && wv == 3 && lane == 63) out[0] = Dcur;  // D[K-1][I-1] == optimal path sum
}

extern "C" void kernel_launch(void* const* d_in, const int* in_sizes, int n_in,
                              void* d_out, int out_size, void* d_ws, size_t ws_size,
                              hipStream_t stream) {
  const float* kern = (const float*)d_in[0]; // (1024,128)
  const float* xx   = (const float*)d_in[1]; // (8192,128)
  char* ws = (char*)d_ws;
  const size_t OFF_X2 = (size_t)NS * SSH * 2;           // c_h: ~16.9 MB
  const size_t OFF_K2 = OFF_X2 + (size_t)IL * 4;
  const size_t OFF_BD = OFF_K2 + (size_t)KL * 4;
  const size_t OFF_FL = OFF_BD + (size_t)NS * IL * 4;
  ushort_t* c_h  = (ushort_t*)ws;
  float* x2    = (float*)(ws + OFF_X2);
  float* k2    = (float*)(ws + OFF_K2);
  float* bnd   = (float*)(ws + OFF_BD);
  int*   flags = (int*)(ws + OFF_FL);

  knorms<<<(IL + KL) / 4, 256, 0, stream>>>(kern, xx, x2, k2, flags);
  kgemm<<<dim3(IL / 64, NS), 256, 0, stream>>>(kern, xx, x2, k2, c_h);
  kdp<<<4, 384, 0, stream>>>(c_h, bnd, flags, (float*)d_out);
}